// Round 5
// baseline (485.098 us; speedup 1.0000x reference)
//
#include <hip/hip_runtime.h>
#include <math.h>

#define IN_CH 128
#define H1N 8
#define C1N 16
#define C2N 64
#define NEG_SLOPE 0.2f

#define BKT_SHIFT 7                 // 128 nodes per bucket
#define BKT_NODES (1 << BKT_SHIFT)
#define BKT_CAP   4096              // mean ~2300, sigma ~47 -> 38 sigma headroom

typedef unsigned short ushortT;

__device__ __forceinline__ ushortT f2bf(float f) {
    unsigned u = __float_as_uint(f);
    unsigned r = u + 0x7FFFu + ((u >> 16) & 1u);
    return (ushortT)(r >> 16);
}
__device__ __forceinline__ float bf2f(ushortT b) {
    return __uint_as_float(((unsigned)b) << 16);
}
__device__ __forceinline__ float leaky(float x) {
    return (x > 0.f) ? x : NEG_SLOPE * x;
}

// ---------------- CSR build (bucket-partitioned) ----------------

// bin edges (+self loops) into dst-range buckets; packed pair = (dstLocal<<16)|src
__global__ void k_bin(const int* __restrict__ src, const int* __restrict__ dst,
                      int E, int N, int* __restrict__ bCnt, unsigned* __restrict__ pair) {
    int stride = gridDim.x * blockDim.x;
    int Etot = E + N;
    for (int i = blockIdx.x * blockDim.x + threadIdx.x; i < Etot; i += stride) {
        int s, d;
        if (i < E) { s = src[i]; d = dst[i]; }
        else       { s = d = i - E; }
        int b = d >> BKT_SHIFT;
        int pos = atomicAdd(&bCnt[b], 1);
        if (pos < BKT_CAP)
            pair[(size_t)b * BKT_CAP + pos] = ((unsigned)(d & (BKT_NODES - 1)) << 16) | (unsigned)s;
    }
}

// single block: exclusive scan of bucket counts -> bucket bases; writes offsets[N]
__global__ void k_scanbucket(const int* __restrict__ bCnt, int nb,
                             int* __restrict__ bBase, int N, int* __restrict__ offsets) {
    __shared__ int sh[512];
    int t = threadIdx.x;
    sh[t] = (t < nb) ? bCnt[t] : 0;
    __syncthreads();
    for (int off = 1; off < 512; off <<= 1) {
        int v = (t >= off) ? sh[t - off] : 0;
        __syncthreads();
        sh[t] += v;
        __syncthreads();
    }
    if (t < nb) bBase[t] = (t == 0) ? 0 : sh[t - 1];
    if (t == 511) offsets[N] = sh[511];
}

// one block per bucket: LDS histogram + scan + cursors -> offsets and uint16 CSR
__global__ __launch_bounds__(256) void k_csr_local(const unsigned* __restrict__ pair,
                                                   const int* __restrict__ bCnt,
                                                   const int* __restrict__ bBase,
                                                   int N, int* __restrict__ offsets,
                                                   ushortT* __restrict__ csr) {
    __shared__ int hist[BKT_NODES];
    __shared__ int loff[BKT_NODES];   // exclusive offsets within bucket
    int b = blockIdx.x;
    int t = threadIdx.x;
    int cnt = bCnt[b];
    if (cnt > BKT_CAP) cnt = BKT_CAP;
    int base = bBase[b];
    const unsigned* pp = pair + (size_t)b * BKT_CAP;

    if (t < BKT_NODES) hist[t] = 0;
    __syncthreads();
    for (int i = t; i < cnt; i += 256) {
        unsigned pk = pp[i];
        atomicAdd(&hist[pk >> 16], 1);
    }
    __syncthreads();
    // inclusive scan of hist into loff (Hillis-Steele over 128, all threads barrier)
    if (t < BKT_NODES) loff[t] = hist[t];
    __syncthreads();
    for (int off = 1; off < BKT_NODES; off <<= 1) {
        int v = 0;
        if (t < BKT_NODES && t >= off) v = loff[t - off];
        __syncthreads();
        if (t < BKT_NODES) loff[t] += v;
        __syncthreads();
    }
    // convert to exclusive: excl[k] = incl[k-1]; reuse hist as running cursor
    int node0 = b << BKT_SHIFT;
    if (t < BKT_NODES) {
        int excl = (t == 0) ? 0 : loff[t];   // careful: need incl[t-1]
    }
    __syncthreads();
    // recompute exclusive properly into hist (cursor) and write offsets
    if (t < BKT_NODES) {
        int excl = (t == 0) ? 0 : loff[t - 1];
        hist[t] = excl;                       // cursor
        int g = node0 + t;
        if (g < N) offsets[g] = base + excl;
    }
    __syncthreads();
    for (int i = t; i < cnt; i += 256) {
        unsigned pk = pp[i];
        int dl = pk >> 16;
        int pos = atomicAdd(&hist[dl], 1);
        csr[base + pos] = (ushortT)(pk & 0xFFFFu);
    }
}

// ---------------- GEMM + fused attention coefficients ----------------

template <int KOUT, int HEADS>
__global__ __launch_bounds__(256) void k_gemm_att(const float* __restrict__ A,
                                                  const float* __restrict__ W,
                                                  const float* __restrict__ att_s,
                                                  const float* __restrict__ att_d,
                                                  int N, ushortT* __restrict__ Cbf,
                                                  float* __restrict__ as_,
                                                  float* __restrict__ ad_) {
    constexpr int CG  = KOUT / 4;
    constexpr int TY  = 256 / CG;
    constexpr int RPT = 64 / TY;
    constexpr int RW  = (KOUT / HEADS) / 4;
    static_assert(RW == 4 || RW == 16, "reduce width");
    __shared__ float As[64][16];
    __shared__ float Ws[16][KOUT];
    int t = threadIdx.x;
    int row0 = blockIdx.x * 64;
    int tx = t % CG, ty = t / CG;

    float4 acc[RPT];
#pragma unroll
    for (int i = 0; i < RPT; ++i) acc[i] = make_float4(0.f, 0.f, 0.f, 0.f);

    for (int k0 = 0; k0 < IN_CH; k0 += 16) {
        {
            int r  = t >> 2;
            int cc = (t & 3) * 4;
            int gr = row0 + r;
            float4 v = make_float4(0.f, 0.f, 0.f, 0.f);
            if (gr < N) v = *(const float4*)(A + (size_t)gr * IN_CH + k0 + cc);
            *(float4*)(&As[r][cc]) = v;
        }
        {
            constexpr int TOT = 16 * KOUT / 4;
            for (int idx = t; idx < TOT; idx += 256) {
                int rr = idx / (KOUT / 4);
                int cc = (idx % (KOUT / 4)) * 4;
                *(float4*)(&Ws[rr][cc]) = *(const float4*)(W + (size_t)(k0 + rr) * KOUT + cc);
            }
        }
        __syncthreads();
#pragma unroll
        for (int kk = 0; kk < 16; ++kk) {
            float4 w = *(const float4*)(&Ws[kk][tx * 4]);
#pragma unroll
            for (int i = 0; i < RPT; ++i) {
                float a = As[ty * RPT + i][kk];
                acc[i].x += a * w.x; acc[i].y += a * w.y;
                acc[i].z += a * w.z; acc[i].w += a * w.w;
            }
        }
        __syncthreads();
    }

    float4 s4 = *(const float4*)(att_s + tx * 4);
    float4 d4 = *(const float4*)(att_d + tx * 4);
#pragma unroll
    for (int i = 0; i < RPT; ++i) {
        int gr = row0 + ty * RPT + i;
        float as = acc[i].x * s4.x + acc[i].y * s4.y + acc[i].z * s4.z + acc[i].w * s4.w;
        float ad = acc[i].x * d4.x + acc[i].y * d4.y + acc[i].z * d4.z + acc[i].w * d4.w;
#pragma unroll
        for (int o = 1; o < RW; o <<= 1) {
            as += __shfl_xor(as, o);
            ad += __shfl_xor(ad, o);
        }
        if (gr < N) {
            ushort4 pk;
            pk.x = f2bf(acc[i].x); pk.y = f2bf(acc[i].y);
            pk.z = f2bf(acc[i].z); pk.w = f2bf(acc[i].w);
            *(ushort4*)(Cbf + (size_t)gr * KOUT + tx * 4) = pk;
            if ((tx % RW) == 0) {
                int h = tx / RW;
                as_[(size_t)gr * HEADS + h] = as;
                ad_[(size_t)gr * HEADS + h] = ad;
            }
        }
    }
}

// ---------------- layer 1 aggregation (+bias +ELU) ----------------

__global__ void k_agg1(const ushortT* __restrict__ h1bf,
                       const float* __restrict__ as1, const float* __restrict__ ad1,
                       const int* __restrict__ offsets, const ushortT* __restrict__ csr,
                       const float* __restrict__ b1,
                       int N, float* __restrict__ h2in) {
    int wid  = (blockIdx.x * blockDim.x + threadIdx.x) >> 6;
    int lane = threadIdx.x & 63;
    if (wid >= N) return;
    int v = wid;
    int hidx = lane >> 3;
    float ad = ad1[v * H1N + hidx];
    float denom = 0.f, acc0 = 0.f, acc1 = 0.f;
    int beg = offsets[v], end = offsets[v + 1];
    int j = beg;
    for (; j + 4 <= end; j += 4) {
        int s0 = csr[j], s1 = csr[j + 1], s2 = csr[j + 2], s3 = csr[j + 3];
        float a0 = as1[s0 * H1N + hidx];
        float a1 = as1[s1 * H1N + hidx];
        float a2 = as1[s2 * H1N + hidx];
        float a3 = as1[s3 * H1N + hidx];
        unsigned q0 = *(const unsigned*)(h1bf + (size_t)s0 * IN_CH + lane * 2);
        unsigned q1 = *(const unsigned*)(h1bf + (size_t)s1 * IN_CH + lane * 2);
        unsigned q2 = *(const unsigned*)(h1bf + (size_t)s2 * IN_CH + lane * 2);
        unsigned q3 = *(const unsigned*)(h1bf + (size_t)s3 * IN_CH + lane * 2);
        float p0 = __expf(leaky(a0 + ad));
        float p1 = __expf(leaky(a1 + ad));
        float p2 = __expf(leaky(a2 + ad));
        float p3 = __expf(leaky(a3 + ad));
        denom += (p0 + p1) + (p2 + p3);
        acc0 = fmaf(p0, bf2f((ushortT)(q0 & 0xFFFFu)), acc0);
        acc1 = fmaf(p0, bf2f((ushortT)(q0 >> 16)), acc1);
        acc0 = fmaf(p1, bf2f((ushortT)(q1 & 0xFFFFu)), acc0);
        acc1 = fmaf(p1, bf2f((ushortT)(q1 >> 16)), acc1);
        acc0 = fmaf(p2, bf2f((ushortT)(q2 & 0xFFFFu)), acc0);
        acc1 = fmaf(p2, bf2f((ushortT)(q2 >> 16)), acc1);
        acc0 = fmaf(p3, bf2f((ushortT)(q3 & 0xFFFFu)), acc0);
        acc1 = fmaf(p3, bf2f((ushortT)(q3 >> 16)), acc1);
    }
    for (; j < end; ++j) {
        int s = csr[j];
        float a = as1[s * H1N + hidx];
        unsigned q = *(const unsigned*)(h1bf + (size_t)s * IN_CH + lane * 2);
        float p = __expf(leaky(a + ad));
        denom += p;
        acc0 = fmaf(p, bf2f((ushortT)(q & 0xFFFFu)), acc0);
        acc1 = fmaf(p, bf2f((ushortT)(q >> 16)), acc1);
    }
    float inv = 1.f / (denom + 1e-16f);
    float o0 = acc0 * inv + b1[lane * 2];
    float o1 = acc1 * inv + b1[lane * 2 + 1];
    o0 = (o0 > 0.f) ? o0 : expm1f(o0);
    o1 = (o1 > 0.f) ? o1 : expm1f(o1);
    float2 ov; ov.x = o0; ov.y = o1;
    *(float2*)(h2in + (size_t)v * IN_CH + lane * 2) = ov;
}

// ---------------- layer 2 aggregation (+bias) + log_softmax ----------------

__global__ void k_agg2(const ushortT* __restrict__ h2bf,
                       const float* __restrict__ as2, const float* __restrict__ ad2,
                       const int* __restrict__ offsets, const ushortT* __restrict__ csr,
                       const float* __restrict__ b2,
                       int N, float* __restrict__ out) {
    int wid  = (blockIdx.x * blockDim.x + threadIdx.x) >> 6;
    int lane = threadIdx.x & 63;
    if (wid >= N) return;
    int v = wid;
    float ad = ad2[v];
    float denom = 0.f, acc = 0.f;
    int beg = offsets[v], end = offsets[v + 1];
    int j = beg;
    for (; j + 4 <= end; j += 4) {
        int s0 = csr[j], s1 = csr[j + 1], s2 = csr[j + 2], s3 = csr[j + 3];
        float a0 = as2[s0], a1 = as2[s1], a2 = as2[s2], a3 = as2[s3];
        float x0 = bf2f(h2bf[(size_t)s0 * C2N + lane]);
        float x1 = bf2f(h2bf[(size_t)s1 * C2N + lane]);
        float x2 = bf2f(h2bf[(size_t)s2 * C2N + lane]);
        float x3 = bf2f(h2bf[(size_t)s3 * C2N + lane]);
        float p0 = __expf(leaky(a0 + ad));
        float p1 = __expf(leaky(a1 + ad));
        float p2 = __expf(leaky(a2 + ad));
        float p3 = __expf(leaky(a3 + ad));
        denom += (p0 + p1) + (p2 + p3);
        acc = fmaf(p0, x0, acc);
        acc = fmaf(p1, x1, acc);
        acc = fmaf(p2, x2, acc);
        acc = fmaf(p3, x3, acc);
    }
    for (; j < end; ++j) {
        int s = csr[j];
        float p = __expf(leaky(as2[s] + ad));
        float x = bf2f(h2bf[(size_t)s * C2N + lane]);
        denom += p;
        acc = fmaf(p, x, acc);
    }
    float o = acc / (denom + 1e-16f) + b2[lane];
    float mx = o;
#pragma unroll
    for (int off = 32; off >= 1; off >>= 1) mx = fmaxf(mx, __shfl_xor(mx, off));
    float e = __expf(o - mx);
    float se = e;
#pragma unroll
    for (int off = 32; off >= 1; off >>= 1) se += __shfl_xor(se, off);
    out[(size_t)v * C2N + lane] = o - mx - logf(se);
}

// ---------------- launch ----------------

extern "C" void kernel_launch(void* const* d_in, const int* in_sizes, int n_in,
                              void* d_out, int out_size, void* d_ws, size_t ws_size,
                              hipStream_t stream) {
    const float* x      = (const float*)d_in[0];
    const int*   ei     = (const int*)d_in[1];
    const float* W1     = (const float*)d_in[2];
    const float* att_s1 = (const float*)d_in[3];
    const float* att_d1 = (const float*)d_in[4];
    const float* b1     = (const float*)d_in[5];
    const float* W2     = (const float*)d_in[6];
    const float* att_s2 = (const float*)d_in[7];
    const float* att_d2 = (const float*)d_in[8];
    const float* b2     = (const float*)d_in[9];

    int N = in_sizes[0] / IN_CH;
    int E = in_sizes[1] / 2;
    const int* srcA = ei;
    const int* dstA = ei + E;
    int Etot = E + N;
    int nb = (N + BKT_NODES - 1) >> BKT_SHIFT;   // 391 buckets for N=50000

    char* p = (char*)d_ws;
    auto carve = [&](size_t bytes) {
        void* r = (void*)p;
        p += (bytes + 255) & ~(size_t)255;
        return r;
    };
    ushortT* h1bf = (ushortT*)carve((size_t)N * IN_CH * 2);
    ushortT* h2bf = (ushortT*)carve((size_t)N * C2N * 2);
    float* h2in = (float*)carve((size_t)N * IN_CH * 4);
    float* as1  = (float*)carve((size_t)N * H1N * 4);
    float* ad1  = (float*)carve((size_t)N * H1N * 4);
    float* as2  = (float*)carve((size_t)N * 4);
    float* ad2  = (float*)carve((size_t)N * 4);
    int* offsets  = (int*)carve((size_t)(N + 1) * 4);
    ushortT* csr  = (ushortT*)carve((size_t)Etot * 2);
    int* bCnt     = (int*)carve((size_t)nb * 4);
    int* bBase    = (int*)carve((size_t)nb * 4);
    unsigned* pair = (unsigned*)carve((size_t)nb * BKT_CAP * 4);

    // CSR build (bucket-partitioned)
    hipMemsetAsync(bCnt, 0, (size_t)nb * 4, stream);
    k_bin<<<2048, 256, 0, stream>>>(srcA, dstA, E, N, bCnt, pair);
    k_scanbucket<<<1, 512, 0, stream>>>(bCnt, nb, bBase, N, offsets);
    k_csr_local<<<nb, 256, 0, stream>>>(pair, bCnt, bBase, N, offsets, csr);

    // layer 1
    k_gemm_att<128, 8><<<(N + 63) / 64, 256, 0, stream>>>(x, W1, att_s1, att_d1,
                                                          N, h1bf, as1, ad1);
    k_agg1<<<(N * 64 + 255) / 256, 256, 0, stream>>>(h1bf, as1, ad1, offsets, csr, b1, N, h2in);

    // layer 2
    k_gemm_att<64, 1><<<(N + 63) / 64, 256, 0, stream>>>(h2in, W2, att_s2, att_d2,
                                                         N, h2bf, as2, ad2);
    k_agg2<<<(N * 64 + 255) / 256, 256, 0, stream>>>(h2bf, as2, ad2, offsets, csr, b2, N, (float*)d_out);
}

// Round 6
// 171.372 us; speedup vs baseline: 2.8307x; 2.8307x over previous
//
#include <hip/hip_runtime.h>
#include <math.h>

#define IN_CH 128
#define H1N 8
#define C1N 16
#define C2N 64
#define NEG_SLOPE 0.2f

#define BKT_SHIFT 7                 // 128 nodes per bucket
#define BKT_NODES (1 << BKT_SHIFT)
#define NBLK 128                    // blocks for count/bin passes

typedef unsigned short ushortT;

__device__ __forceinline__ ushortT f2bf(float f) {
    unsigned u = __float_as_uint(f);
    unsigned r = u + 0x7FFFu + ((u >> 16) & 1u);
    return (ushortT)(r >> 16);
}
__device__ __forceinline__ float bf2f(ushortT b) {
    return __uint_as_float(((unsigned)b) << 16);
}
__device__ __forceinline__ float leaky(float x) {
    return (x > 0.f) ? x : NEG_SLOPE * x;
}

// ---------------- CSR build: deterministic counting sort, no global atomics ----------------

// pass A: per-block LDS histogram over buckets -> cnt[bucket][block]
__global__ __launch_bounds__(512) void k_cnt(const int* __restrict__ src,
                                             const int* __restrict__ dst,
                                             int E, int N, int* __restrict__ cnt) {
    __shared__ int hist[512];
    int blk = blockIdx.x, t = threadIdx.x;
    int nb = (N + BKT_NODES - 1) >> BKT_SHIFT;
    if (t < nb) hist[t] = 0;
    __syncthreads();
    int Etot = E + N;
    int chunk = (Etot + gridDim.x - 1) / gridDim.x;
    int lo = blk * chunk;
    int hi = lo + chunk; if (hi > Etot) hi = Etot;
    for (int i = lo + t; i < hi; i += 512) {
        int d = (i < E) ? dst[i] : (i - E);
        atomicAdd(&hist[d >> BKT_SHIFT], 1);
    }
    __syncthreads();
    if (t < nb) cnt[t * NBLK + blk] = hist[t];
}

// pass B1: per bucket, exclusive scan of its NBLK block-counts (in place) + bucket total
__global__ __launch_bounds__(NBLK) void k_scanrel(int* __restrict__ cnt,
                                                  int* __restrict__ bucketTotal) {
    __shared__ int sh[NBLK];
    int b = blockIdx.x, t = threadIdx.x;
    sh[t] = cnt[b * NBLK + t];
    __syncthreads();
    for (int off = 1; off < NBLK; off <<= 1) {
        int v = (t >= off) ? sh[t - off] : 0;
        __syncthreads();
        sh[t] += v;
        __syncthreads();
    }
    if (t == NBLK - 1) bucketTotal[b] = sh[t];
    cnt[b * NBLK + t] = (t == 0) ? 0 : sh[t - 1];
}

// pass B2: single block scan of bucket totals -> bBase (exclusive), bBase[nb]=total, offsets[N]=total
__global__ __launch_bounds__(512) void k_scanbucket(const int* __restrict__ bucketTotal,
                                                    int nb, int* __restrict__ bBase,
                                                    int N, int* __restrict__ offsets) {
    __shared__ int sh[512];
    int t = threadIdx.x;
    sh[t] = (t < nb) ? bucketTotal[t] : 0;
    __syncthreads();
    for (int off = 1; off < 512; off <<= 1) {
        int v = (t >= off) ? sh[t - off] : 0;
        __syncthreads();
        sh[t] += v;
        __syncthreads();
    }
    if (t < nb) bBase[t] = (t == 0) ? 0 : sh[t - 1];
    if (t == 511) { bBase[nb] = sh[511]; offsets[N] = sh[511]; }
}

// pass C: re-read edges, write packed pairs densely via LDS cursors (no global atomics)
__global__ __launch_bounds__(512) void k_bin(const int* __restrict__ src,
                                             const int* __restrict__ dst,
                                             int E, int N,
                                             const int* __restrict__ cnt,
                                             const int* __restrict__ bBase,
                                             unsigned* __restrict__ pair) {
    __shared__ int cur[512];
    int blk = blockIdx.x, t = threadIdx.x;
    int nb = (N + BKT_NODES - 1) >> BKT_SHIFT;
    if (t < nb) cur[t] = bBase[t] + cnt[t * NBLK + blk];
    __syncthreads();
    int Etot = E + N;
    int chunk = (Etot + gridDim.x - 1) / gridDim.x;
    int lo = blk * chunk;
    int hi = lo + chunk; if (hi > Etot) hi = Etot;
    for (int i = lo + t; i < hi; i += 512) {
        int s, d;
        if (i < E) { s = src[i]; d = dst[i]; }
        else       { s = d = i - E; }
        int b = d >> BKT_SHIFT;
        int pos = atomicAdd(&cur[b], 1);
        pair[pos] = ((unsigned)(d & (BKT_NODES - 1)) << 16) | (unsigned)s;
    }
}

// one block per bucket: LDS histogram + scan + cursors -> offsets and uint16 CSR
__global__ __launch_bounds__(256) void k_csr_local(const unsigned* __restrict__ pair,
                                                   const int* __restrict__ bBase,
                                                   int N, int* __restrict__ offsets,
                                                   ushortT* __restrict__ csr) {
    __shared__ int hist[BKT_NODES];
    __shared__ int loff[BKT_NODES];
    int b = blockIdx.x;
    int t = threadIdx.x;
    int base = bBase[b];
    int cnt = bBase[b + 1] - base;
    const unsigned* pp = pair + base;

    if (t < BKT_NODES) hist[t] = 0;
    __syncthreads();
    for (int i = t; i < cnt; i += 256) atomicAdd(&hist[pp[i] >> 16], 1);
    __syncthreads();
    if (t < BKT_NODES) loff[t] = hist[t];
    __syncthreads();
    for (int off = 1; off < BKT_NODES; off <<= 1) {
        int v = 0;
        if (t < BKT_NODES && t >= off) v = loff[t - off];
        __syncthreads();
        if (t < BKT_NODES) loff[t] += v;
        __syncthreads();
    }
    int node0 = b << BKT_SHIFT;
    if (t < BKT_NODES) {
        int excl = (t == 0) ? 0 : loff[t - 1];
        hist[t] = excl;                       // running cursor
        int g = node0 + t;
        if (g < N) offsets[g] = base + excl;
    }
    __syncthreads();
    for (int i = t; i < cnt; i += 256) {
        unsigned pk = pp[i];
        int pos = atomicAdd(&hist[pk >> 16], 1);
        csr[base + pos] = (ushortT)(pk & 0xFFFFu);
    }
}

// ---------------- GEMM + fused attention coefficients ----------------

template <int KOUT, int HEADS>
__global__ __launch_bounds__(256) void k_gemm_att(const float* __restrict__ A,
                                                  const float* __restrict__ W,
                                                  const float* __restrict__ att_s,
                                                  const float* __restrict__ att_d,
                                                  int N, ushortT* __restrict__ Cbf,
                                                  float* __restrict__ as_,
                                                  float* __restrict__ ad_) {
    constexpr int CG  = KOUT / 4;
    constexpr int TY  = 256 / CG;
    constexpr int RPT = 64 / TY;
    constexpr int RW  = (KOUT / HEADS) / 4;
    static_assert(RW == 4 || RW == 16, "reduce width");
    __shared__ float As[64][16];
    __shared__ float Ws[16][KOUT];
    int t = threadIdx.x;
    int row0 = blockIdx.x * 64;
    int tx = t % CG, ty = t / CG;

    float4 acc[RPT];
#pragma unroll
    for (int i = 0; i < RPT; ++i) acc[i] = make_float4(0.f, 0.f, 0.f, 0.f);

    for (int k0 = 0; k0 < IN_CH; k0 += 16) {
        {
            int r  = t >> 2;
            int cc = (t & 3) * 4;
            int gr = row0 + r;
            float4 v = make_float4(0.f, 0.f, 0.f, 0.f);
            if (gr < N) v = *(const float4*)(A + (size_t)gr * IN_CH + k0 + cc);
            *(float4*)(&As[r][cc]) = v;
        }
        {
            constexpr int TOT = 16 * KOUT / 4;
            for (int idx = t; idx < TOT; idx += 256) {
                int rr = idx / (KOUT / 4);
                int cc = (idx % (KOUT / 4)) * 4;
                *(float4*)(&Ws[rr][cc]) = *(const float4*)(W + (size_t)(k0 + rr) * KOUT + cc);
            }
        }
        __syncthreads();
#pragma unroll
        for (int kk = 0; kk < 16; ++kk) {
            float4 w = *(const float4*)(&Ws[kk][tx * 4]);
#pragma unroll
            for (int i = 0; i < RPT; ++i) {
                float a = As[ty * RPT + i][kk];
                acc[i].x += a * w.x; acc[i].y += a * w.y;
                acc[i].z += a * w.z; acc[i].w += a * w.w;
            }
        }
        __syncthreads();
    }

    float4 s4 = *(const float4*)(att_s + tx * 4);
    float4 d4 = *(const float4*)(att_d + tx * 4);
#pragma unroll
    for (int i = 0; i < RPT; ++i) {
        int gr = row0 + ty * RPT + i;
        float as = acc[i].x * s4.x + acc[i].y * s4.y + acc[i].z * s4.z + acc[i].w * s4.w;
        float ad = acc[i].x * d4.x + acc[i].y * d4.y + acc[i].z * d4.z + acc[i].w * d4.w;
#pragma unroll
        for (int o = 1; o < RW; o <<= 1) {
            as += __shfl_xor(as, o);
            ad += __shfl_xor(ad, o);
        }
        if (gr < N) {
            ushort4 pk;
            pk.x = f2bf(acc[i].x); pk.y = f2bf(acc[i].y);
            pk.z = f2bf(acc[i].z); pk.w = f2bf(acc[i].w);
            *(ushort4*)(Cbf + (size_t)gr * KOUT + tx * 4) = pk;
            if ((tx % RW) == 0) {
                int h = tx / RW;
                as_[(size_t)gr * HEADS + h] = as;
                ad_[(size_t)gr * HEADS + h] = ad;
            }
        }
    }
}

// ---------------- layer 1 aggregation (+bias +ELU) ----------------

__global__ void k_agg1(const ushortT* __restrict__ h1bf,
                       const float* __restrict__ as1, const float* __restrict__ ad1,
                       const int* __restrict__ offsets, const ushortT* __restrict__ csr,
                       const float* __restrict__ b1,
                       int N, float* __restrict__ h2in) {
    int wid  = (blockIdx.x * blockDim.x + threadIdx.x) >> 6;
    int lane = threadIdx.x & 63;
    if (wid >= N) return;
    int v = wid;
    int hidx = lane >> 3;
    float ad = ad1[v * H1N + hidx];
    float denom = 0.f, acc0 = 0.f, acc1 = 0.f;
    int beg = offsets[v], end = offsets[v + 1];
    int j = beg;
    for (; j + 4 <= end; j += 4) {
        int s0 = csr[j], s1 = csr[j + 1], s2 = csr[j + 2], s3 = csr[j + 3];
        float a0 = as1[s0 * H1N + hidx];
        float a1 = as1[s1 * H1N + hidx];
        float a2 = as1[s2 * H1N + hidx];
        float a3 = as1[s3 * H1N + hidx];
        unsigned q0 = *(const unsigned*)(h1bf + (size_t)s0 * IN_CH + lane * 2);
        unsigned q1 = *(const unsigned*)(h1bf + (size_t)s1 * IN_CH + lane * 2);
        unsigned q2 = *(const unsigned*)(h1bf + (size_t)s2 * IN_CH + lane * 2);
        unsigned q3 = *(const unsigned*)(h1bf + (size_t)s3 * IN_CH + lane * 2);
        float p0 = __expf(leaky(a0 + ad));
        float p1 = __expf(leaky(a1 + ad));
        float p2 = __expf(leaky(a2 + ad));
        float p3 = __expf(leaky(a3 + ad));
        denom += (p0 + p1) + (p2 + p3);
        acc0 = fmaf(p0, bf2f((ushortT)(q0 & 0xFFFFu)), acc0);
        acc1 = fmaf(p0, bf2f((ushortT)(q0 >> 16)), acc1);
        acc0 = fmaf(p1, bf2f((ushortT)(q1 & 0xFFFFu)), acc0);
        acc1 = fmaf(p1, bf2f((ushortT)(q1 >> 16)), acc1);
        acc0 = fmaf(p2, bf2f((ushortT)(q2 & 0xFFFFu)), acc0);
        acc1 = fmaf(p2, bf2f((ushortT)(q2 >> 16)), acc1);
        acc0 = fmaf(p3, bf2f((ushortT)(q3 & 0xFFFFu)), acc0);
        acc1 = fmaf(p3, bf2f((ushortT)(q3 >> 16)), acc1);
    }
    for (; j < end; ++j) {
        int s = csr[j];
        float a = as1[s * H1N + hidx];
        unsigned q = *(const unsigned*)(h1bf + (size_t)s * IN_CH + lane * 2);
        float p = __expf(leaky(a + ad));
        denom += p;
        acc0 = fmaf(p, bf2f((ushortT)(q & 0xFFFFu)), acc0);
        acc1 = fmaf(p, bf2f((ushortT)(q >> 16)), acc1);
    }
    float inv = 1.f / (denom + 1e-16f);
    float o0 = acc0 * inv + b1[lane * 2];
    float o1 = acc1 * inv + b1[lane * 2 + 1];
    o0 = (o0 > 0.f) ? o0 : expm1f(o0);
    o1 = (o1 > 0.f) ? o1 : expm1f(o1);
    float2 ov; ov.x = o0; ov.y = o1;
    *(float2*)(h2in + (size_t)v * IN_CH + lane * 2) = ov;
}

// ---------------- layer 2 aggregation (+bias) + log_softmax ----------------

__global__ void k_agg2(const ushortT* __restrict__ h2bf,
                       const float* __restrict__ as2, const float* __restrict__ ad2,
                       const int* __restrict__ offsets, const ushortT* __restrict__ csr,
                       const float* __restrict__ b2,
                       int N, float* __restrict__ out) {
    int wid  = (blockIdx.x * blockDim.x + threadIdx.x) >> 6;
    int lane = threadIdx.x & 63;
    if (wid >= N) return;
    int v = wid;
    float ad = ad2[v];
    float denom = 0.f, acc = 0.f;
    int beg = offsets[v], end = offsets[v + 1];
    int j = beg;
    for (; j + 4 <= end; j += 4) {
        int s0 = csr[j], s1 = csr[j + 1], s2 = csr[j + 2], s3 = csr[j + 3];
        float a0 = as2[s0], a1 = as2[s1], a2 = as2[s2], a3 = as2[s3];
        float x0 = bf2f(h2bf[(size_t)s0 * C2N + lane]);
        float x1 = bf2f(h2bf[(size_t)s1 * C2N + lane]);
        float x2 = bf2f(h2bf[(size_t)s2 * C2N + lane]);
        float x3 = bf2f(h2bf[(size_t)s3 * C2N + lane]);
        float p0 = __expf(leaky(a0 + ad));
        float p1 = __expf(leaky(a1 + ad));
        float p2 = __expf(leaky(a2 + ad));
        float p3 = __expf(leaky(a3 + ad));
        denom += (p0 + p1) + (p2 + p3);
        acc = fmaf(p0, x0, acc);
        acc = fmaf(p1, x1, acc);
        acc = fmaf(p2, x2, acc);
        acc = fmaf(p3, x3, acc);
    }
    for (; j < end; ++j) {
        int s = csr[j];
        float p = __expf(leaky(as2[s] + ad));
        float x = bf2f(h2bf[(size_t)s * C2N + lane]);
        denom += p;
        acc = fmaf(p, x, acc);
    }
    float o = acc / (denom + 1e-16f) + b2[lane];
    float mx = o;
#pragma unroll
    for (int off = 32; off >= 1; off >>= 1) mx = fmaxf(mx, __shfl_xor(mx, off));
    float e = __expf(o - mx);
    float se = e;
#pragma unroll
    for (int off = 32; off >= 1; off >>= 1) se += __shfl_xor(se, off);
    out[(size_t)v * C2N + lane] = o - mx - logf(se);
}

// ---------------- launch ----------------

extern "C" void kernel_launch(void* const* d_in, const int* in_sizes, int n_in,
                              void* d_out, int out_size, void* d_ws, size_t ws_size,
                              hipStream_t stream) {
    const float* x      = (const float*)d_in[0];
    const int*   ei     = (const int*)d_in[1];
    const float* W1     = (const float*)d_in[2];
    const float* att_s1 = (const float*)d_in[3];
    const float* att_d1 = (const float*)d_in[4];
    const float* b1     = (const float*)d_in[5];
    const float* W2     = (const float*)d_in[6];
    const float* att_s2 = (const float*)d_in[7];
    const float* att_d2 = (const float*)d_in[8];
    const float* b2     = (const float*)d_in[9];

    int N = in_sizes[0] / IN_CH;
    int E = in_sizes[1] / 2;
    const int* srcA = ei;
    const int* dstA = ei + E;
    int Etot = E + N;
    int nb = (N + BKT_NODES - 1) >> BKT_SHIFT;   // 391 buckets for N=50000 (<=512)

    char* p = (char*)d_ws;
    auto carve = [&](size_t bytes) {
        void* r = (void*)p;
        p += (bytes + 255) & ~(size_t)255;
        return r;
    };
    ushortT* h1bf = (ushortT*)carve((size_t)N * IN_CH * 2);
    ushortT* h2bf = (ushortT*)carve((size_t)N * C2N * 2);
    float* h2in = (float*)carve((size_t)N * IN_CH * 4);
    float* as1  = (float*)carve((size_t)N * H1N * 4);
    float* ad1  = (float*)carve((size_t)N * H1N * 4);
    float* as2  = (float*)carve((size_t)N * 4);
    float* ad2  = (float*)carve((size_t)N * 4);
    int* offsets     = (int*)carve((size_t)(N + 1) * 4);
    ushortT* csr     = (ushortT*)carve((size_t)Etot * 2);
    int* cnt         = (int*)carve((size_t)nb * NBLK * 4);
    int* bucketTotal = (int*)carve((size_t)nb * 4);
    int* bBase       = (int*)carve((size_t)(nb + 1) * 4);
    unsigned* pair   = (unsigned*)carve((size_t)Etot * 4);

    // CSR build (deterministic counting sort; no global atomics)
    k_cnt<<<NBLK, 512, 0, stream>>>(srcA, dstA, E, N, cnt);
    k_scanrel<<<nb, NBLK, 0, stream>>>(cnt, bucketTotal);
    k_scanbucket<<<1, 512, 0, stream>>>(bucketTotal, nb, bBase, N, offsets);
    k_bin<<<NBLK, 512, 0, stream>>>(srcA, dstA, E, N, cnt, bBase, pair);
    k_csr_local<<<nb, 256, 0, stream>>>(pair, bBase, N, offsets, csr);

    // layer 1
    k_gemm_att<128, 8><<<(N + 63) / 64, 256, 0, stream>>>(x, W1, att_s1, att_d1,
                                                          N, h1bf, as1, ad1);
    k_agg1<<<(N * 64 + 255) / 256, 256, 0, stream>>>(h1bf, as1, ad1, offsets, csr, b1, N, h2in);

    // layer 2
    k_gemm_att<64, 1><<<(N + 63) / 64, 256, 0, stream>>>(h2in, W2, att_s2, att_d2,
                                                         N, h2bf, as2, ad2);
    k_agg2<<<(N * 64 + 255) / 256, 256, 0, stream>>>(h2bf, as2, ad2, offsets, csr, b2, N, (float*)d_out);
}

// Round 7
// 164.898 us; speedup vs baseline: 2.9418x; 1.0393x over previous
//
#include <hip/hip_runtime.h>
#include <math.h>

#define IN_CH 128
#define H1N 8
#define C1N 16
#define C2N 64
#define NEG_SLOPE 0.2f

#define BKT_SHIFT 7                 // 128 nodes per bucket
#define BKT_NODES (1 << BKT_SHIFT)
#define NBLK 128                    // blocks for count/bin passes

typedef unsigned short ushortT;

__device__ __forceinline__ ushortT f2bf(float f) {
    unsigned u = __float_as_uint(f);
    unsigned r = u + 0x7FFFu + ((u >> 16) & 1u);
    return (ushortT)(r >> 16);
}
__device__ __forceinline__ float bf2f(ushortT b) {
    return __uint_as_float(((unsigned)b) << 16);
}
__device__ __forceinline__ float leaky(float x) {
    return (x > 0.f) ? x : NEG_SLOPE * x;
}

// ---------------- CSR build: deterministic counting sort, no global atomics ----------------

__global__ __launch_bounds__(512) void k_cnt(const int* __restrict__ src,
                                             const int* __restrict__ dst,
                                             int E, int N, int* __restrict__ cnt) {
    __shared__ int hist[512];
    int blk = blockIdx.x, t = threadIdx.x;
    int nb = (N + BKT_NODES - 1) >> BKT_SHIFT;
    if (t < nb) hist[t] = 0;
    __syncthreads();
    int Etot = E + N;
    int chunk = (Etot + gridDim.x - 1) / gridDim.x;
    int lo = blk * chunk;
    int hi = lo + chunk; if (hi > Etot) hi = Etot;
    for (int i = lo + t; i < hi; i += 512) {
        int d = (i < E) ? dst[i] : (i - E);
        atomicAdd(&hist[d >> BKT_SHIFT], 1);
    }
    __syncthreads();
    if (t < nb) cnt[t * NBLK + blk] = hist[t];
}

__global__ __launch_bounds__(NBLK) void k_scanrel(int* __restrict__ cnt,
                                                  int* __restrict__ bucketTotal) {
    __shared__ int sh[NBLK];
    int b = blockIdx.x, t = threadIdx.x;
    sh[t] = cnt[b * NBLK + t];
    __syncthreads();
    for (int off = 1; off < NBLK; off <<= 1) {
        int v = (t >= off) ? sh[t - off] : 0;
        __syncthreads();
        sh[t] += v;
        __syncthreads();
    }
    if (t == NBLK - 1) bucketTotal[b] = sh[t];
    cnt[b * NBLK + t] = (t == 0) ? 0 : sh[t - 1];
}

__global__ __launch_bounds__(512) void k_scanbucket(const int* __restrict__ bucketTotal,
                                                    int nb, int* __restrict__ bBase,
                                                    int N, int* __restrict__ offsets) {
    __shared__ int sh[512];
    int t = threadIdx.x;
    sh[t] = (t < nb) ? bucketTotal[t] : 0;
    __syncthreads();
    for (int off = 1; off < 512; off <<= 1) {
        int v = (t >= off) ? sh[t - off] : 0;
        __syncthreads();
        sh[t] += v;
        __syncthreads();
    }
    if (t < nb) bBase[t] = (t == 0) ? 0 : sh[t - 1];
    if (t == 511) { bBase[nb] = sh[511]; offsets[N] = sh[511]; }
}

__global__ __launch_bounds__(512) void k_bin(const int* __restrict__ src,
                                             const int* __restrict__ dst,
                                             int E, int N,
                                             const int* __restrict__ cnt,
                                             const int* __restrict__ bBase,
                                             unsigned* __restrict__ pair) {
    __shared__ int cur[512];
    int blk = blockIdx.x, t = threadIdx.x;
    int nb = (N + BKT_NODES - 1) >> BKT_SHIFT;
    if (t < nb) cur[t] = bBase[t] + cnt[t * NBLK + blk];
    __syncthreads();
    int Etot = E + N;
    int chunk = (Etot + gridDim.x - 1) / gridDim.x;
    int lo = blk * chunk;
    int hi = lo + chunk; if (hi > Etot) hi = Etot;
    for (int i = lo + t; i < hi; i += 512) {
        int s, d;
        if (i < E) { s = src[i]; d = dst[i]; }
        else       { s = d = i - E; }
        int b = d >> BKT_SHIFT;
        int pos = atomicAdd(&cur[b], 1);
        pair[pos] = ((unsigned)(d & (BKT_NODES - 1)) << 16) | (unsigned)s;
    }
}

__global__ __launch_bounds__(256) void k_csr_local(const unsigned* __restrict__ pair,
                                                   const int* __restrict__ bBase,
                                                   int N, int* __restrict__ offsets,
                                                   ushortT* __restrict__ csr) {
    __shared__ int hist[BKT_NODES];
    __shared__ int loff[BKT_NODES];
    int b = blockIdx.x;
    int t = threadIdx.x;
    int base = bBase[b];
    int cnt = bBase[b + 1] - base;
    const unsigned* pp = pair + base;

    if (t < BKT_NODES) hist[t] = 0;
    __syncthreads();
    for (int i = t; i < cnt; i += 256) atomicAdd(&hist[pp[i] >> 16], 1);
    __syncthreads();
    if (t < BKT_NODES) loff[t] = hist[t];
    __syncthreads();
    for (int off = 1; off < BKT_NODES; off <<= 1) {
        int v = 0;
        if (t < BKT_NODES && t >= off) v = loff[t - off];
        __syncthreads();
        if (t < BKT_NODES) loff[t] += v;
        __syncthreads();
    }
    int node0 = b << BKT_SHIFT;
    if (t < BKT_NODES) {
        int excl = (t == 0) ? 0 : loff[t - 1];
        hist[t] = excl;
        int g = node0 + t;
        if (g < N) offsets[g] = base + excl;
    }
    __syncthreads();
    for (int i = t; i < cnt; i += 256) {
        unsigned pk = pp[i];
        int pos = atomicAdd(&hist[pk >> 16], 1);
        csr[base + pos] = (ushortT)(pk & 0xFFFFu);
    }
}

// ---------------- GEMM + fused attention coefficients ----------------

template <int KOUT, int HEADS>
__global__ __launch_bounds__(256) void k_gemm_att(const float* __restrict__ A,
                                                  const float* __restrict__ W,
                                                  const float* __restrict__ att_s,
                                                  const float* __restrict__ att_d,
                                                  int N, ushortT* __restrict__ Cbf,
                                                  float* __restrict__ as_,
                                                  float* __restrict__ ad_) {
    constexpr int CG  = KOUT / 4;
    constexpr int TY  = 256 / CG;
    constexpr int RPT = 64 / TY;
    constexpr int RW  = (KOUT / HEADS) / 4;
    static_assert(RW == 4 || RW == 16, "reduce width");
    __shared__ float As[64][16];
    __shared__ float Ws[16][KOUT];
    int t = threadIdx.x;
    int row0 = blockIdx.x * 64;
    int tx = t % CG, ty = t / CG;

    float4 acc[RPT];
#pragma unroll
    for (int i = 0; i < RPT; ++i) acc[i] = make_float4(0.f, 0.f, 0.f, 0.f);

    for (int k0 = 0; k0 < IN_CH; k0 += 16) {
        {
            int r  = t >> 2;
            int cc = (t & 3) * 4;
            int gr = row0 + r;
            float4 v = make_float4(0.f, 0.f, 0.f, 0.f);
            if (gr < N) v = *(const float4*)(A + (size_t)gr * IN_CH + k0 + cc);
            *(float4*)(&As[r][cc]) = v;
        }
        {
            constexpr int TOT = 16 * KOUT / 4;
            for (int idx = t; idx < TOT; idx += 256) {
                int rr = idx / (KOUT / 4);
                int cc = (idx % (KOUT / 4)) * 4;
                *(float4*)(&Ws[rr][cc]) = *(const float4*)(W + (size_t)(k0 + rr) * KOUT + cc);
            }
        }
        __syncthreads();
#pragma unroll
        for (int kk = 0; kk < 16; ++kk) {
            float4 w = *(const float4*)(&Ws[kk][tx * 4]);
#pragma unroll
            for (int i = 0; i < RPT; ++i) {
                float a = As[ty * RPT + i][kk];
                acc[i].x += a * w.x; acc[i].y += a * w.y;
                acc[i].z += a * w.z; acc[i].w += a * w.w;
            }
        }
        __syncthreads();
    }

    float4 s4 = *(const float4*)(att_s + tx * 4);
    float4 d4 = *(const float4*)(att_d + tx * 4);
#pragma unroll
    for (int i = 0; i < RPT; ++i) {
        int gr = row0 + ty * RPT + i;
        float as = acc[i].x * s4.x + acc[i].y * s4.y + acc[i].z * s4.z + acc[i].w * s4.w;
        float ad = acc[i].x * d4.x + acc[i].y * d4.y + acc[i].z * d4.z + acc[i].w * d4.w;
#pragma unroll
        for (int o = 1; o < RW; o <<= 1) {
            as += __shfl_xor(as, o);
            ad += __shfl_xor(ad, o);
        }
        if (gr < N) {
            ushort4 pk;
            pk.x = f2bf(acc[i].x); pk.y = f2bf(acc[i].y);
            pk.z = f2bf(acc[i].z); pk.w = f2bf(acc[i].w);
            *(ushort4*)(Cbf + (size_t)gr * KOUT + tx * 4) = pk;
            if ((tx % RW) == 0) {
                int h = tx / RW;
                as_[(size_t)gr * HEADS + h] = as;
                ad_[(size_t)gr * HEADS + h] = ad;
            }
        }
    }
}

// ---------------- layer 1 aggregation (+bias +ELU) ----------------
// wave per node; lane owns channels 2*lane,2*lane+1 (consumer head hc=lane>>3).
// Producer role: lane computes p for (edge = lane>>3, head = lane&7) of the
// 8-edge batch -> one exp per (edge,head) instead of 8 duplicates; values
// distributed via __shfl (DS pipe, off the VALU).

__global__ void k_agg1(const ushortT* __restrict__ h1bf,
                       const float* __restrict__ as1, const float* __restrict__ ad1,
                       const int* __restrict__ offsets, const ushortT* __restrict__ csr,
                       const float* __restrict__ b1,
                       int N, float* __restrict__ h2in) {
    int wid  = (blockIdx.x * blockDim.x + threadIdx.x) >> 6;
    int lane = threadIdx.x & 63;
    if (wid >= N) return;
    int v = wid;
    int hc = lane >> 3;               // consumer head
    int hp = lane & 7;                // producer head
    float adc = ad1[v * H1N + hc];
    float adp = ad1[v * H1N + hp];
    float denom = 0.f, acc0 = 0.f, acc1 = 0.f;
    int beg = offsets[v], end = offsets[v + 1];
    int j = beg;
    for (; j + 8 <= end; j += 8) {
        int ep = lane >> 3;                       // producer edge 0..7
        int sE = csr[j + ep];
        float a = as1[sE * H1N + hp];
        float pp = __expf(leaky(a + adp));
#pragma unroll
        for (int e = 0; e < 8; ++e) {
            int srcl = e * 8 + hc;
            float pe = __shfl(pp, srcl);
            int   se = __shfl(sE, srcl);
            unsigned q = *(const unsigned*)(h1bf + (size_t)se * IN_CH + lane * 2);
            denom += pe;
            acc0 = fmaf(pe, bf2f((ushortT)(q & 0xFFFFu)), acc0);
            acc1 = fmaf(pe, bf2f((ushortT)(q >> 16)), acc1);
        }
    }
    if (j + 4 <= end) {
        int ep = (lane >> 3) & 3;                 // producer edge 0..3 (dup in hi half)
        int sE = csr[j + ep];
        float a = as1[sE * H1N + hp];
        float pp = __expf(leaky(a + adp));
#pragma unroll
        for (int e = 0; e < 4; ++e) {
            int srcl = e * 8 + hc;
            float pe = __shfl(pp, srcl);
            int   se = __shfl(sE, srcl);
            unsigned q = *(const unsigned*)(h1bf + (size_t)se * IN_CH + lane * 2);
            denom += pe;
            acc0 = fmaf(pe, bf2f((ushortT)(q & 0xFFFFu)), acc0);
            acc1 = fmaf(pe, bf2f((ushortT)(q >> 16)), acc1);
        }
        j += 4;
    }
    for (; j < end; ++j) {
        int s = csr[j];
        float a = as1[s * H1N + hc];
        unsigned q = *(const unsigned*)(h1bf + (size_t)s * IN_CH + lane * 2);
        float p = __expf(leaky(a + adc));
        denom += p;
        acc0 = fmaf(p, bf2f((ushortT)(q & 0xFFFFu)), acc0);
        acc1 = fmaf(p, bf2f((ushortT)(q >> 16)), acc1);
    }
    float inv = 1.f / (denom + 1e-16f);
    float o0 = acc0 * inv + b1[lane * 2];
    float o1 = acc1 * inv + b1[lane * 2 + 1];
    o0 = (o0 > 0.f) ? o0 : expm1f(o0);
    o1 = (o1 > 0.f) ? o1 : expm1f(o1);
    float2 ov; ov.x = o0; ov.y = o1;
    *(float2*)(h2in + (size_t)v * IN_CH + lane * 2) = ov;
}

// ---------------- layer 2 aggregation (+bias) + log_softmax ----------------
// wave per node; lane owns channel lane. Producer: lane computes p for
// edge = lane&7 of the 8-edge batch (one exp per edge instead of 64).

__global__ void k_agg2(const ushortT* __restrict__ h2bf,
                       const float* __restrict__ as2, const float* __restrict__ ad2,
                       const int* __restrict__ offsets, const ushortT* __restrict__ csr,
                       const float* __restrict__ b2,
                       int N, float* __restrict__ out) {
    int wid  = (blockIdx.x * blockDim.x + threadIdx.x) >> 6;
    int lane = threadIdx.x & 63;
    if (wid >= N) return;
    int v = wid;
    float ad = ad2[v];
    float denom = 0.f, acc = 0.f;
    int beg = offsets[v], end = offsets[v + 1];
    int j = beg;
    for (; j + 8 <= end; j += 8) {
        int ep = lane & 7;
        int sE = csr[j + ep];
        float pp = __expf(leaky(as2[sE] + ad));
#pragma unroll
        for (int e = 0; e < 8; ++e) {
            float pe = __shfl(pp, e);             // lane e holds edge e
            int   se = __shfl(sE, e);
            float x = bf2f(h2bf[(size_t)se * C2N + lane]);
            denom += pe;
            acc = fmaf(pe, x, acc);
        }
    }
    for (; j < end; ++j) {
        int s = csr[j];
        float p = __expf(leaky(as2[s] + ad));
        float x = bf2f(h2bf[(size_t)s * C2N + lane]);
        denom += p;
        acc = fmaf(p, x, acc);
    }
    float o = acc / (denom + 1e-16f) + b2[lane];
    float mx = o;
#pragma unroll
    for (int off = 32; off >= 1; off >>= 1) mx = fmaxf(mx, __shfl_xor(mx, off));
    float e = __expf(o - mx);
    float se = e;
#pragma unroll
    for (int off = 32; off >= 1; off >>= 1) se += __shfl_xor(se, off);
    out[(size_t)v * C2N + lane] = o - mx - logf(se);
}

// ---------------- launch ----------------

extern "C" void kernel_launch(void* const* d_in, const int* in_sizes, int n_in,
                              void* d_out, int out_size, void* d_ws, size_t ws_size,
                              hipStream_t stream) {
    const float* x      = (const float*)d_in[0];
    const int*   ei     = (const int*)d_in[1];
    const float* W1     = (const float*)d_in[2];
    const float* att_s1 = (const float*)d_in[3];
    const float* att_d1 = (const float*)d_in[4];
    const float* b1     = (const float*)d_in[5];
    const float* W2     = (const float*)d_in[6];
    const float* att_s2 = (const float*)d_in[7];
    const float* att_d2 = (const float*)d_in[8];
    const float* b2     = (const float*)d_in[9];

    int N = in_sizes[0] / IN_CH;
    int E = in_sizes[1] / 2;
    const int* srcA = ei;
    const int* dstA = ei + E;
    int Etot = E + N;
    int nb = (N + BKT_NODES - 1) >> BKT_SHIFT;

    char* p = (char*)d_ws;
    auto carve = [&](size_t bytes) {
        void* r = (void*)p;
        p += (bytes + 255) & ~(size_t)255;
        return r;
    };
    ushortT* h1bf = (ushortT*)carve((size_t)N * IN_CH * 2);
    ushortT* h2bf = (ushortT*)carve((size_t)N * C2N * 2);
    float* h2in = (float*)carve((size_t)N * IN_CH * 4);
    float* as1  = (float*)carve((size_t)N * H1N * 4);
    float* ad1  = (float*)carve((size_t)N * H1N * 4);
    float* as2  = (float*)carve((size_t)N * 4);
    float* ad2  = (float*)carve((size_t)N * 4);
    int* offsets     = (int*)carve((size_t)(N + 1) * 4);
    ushortT* csr     = (ushortT*)carve((size_t)Etot * 2);
    int* cnt         = (int*)carve((size_t)nb * NBLK * 4);
    int* bucketTotal = (int*)carve((size_t)nb * 4);
    int* bBase       = (int*)carve((size_t)(nb + 1) * 4);
    unsigned* pair   = (unsigned*)carve((size_t)Etot * 4);

    // CSR build (deterministic counting sort; no global atomics)
    k_cnt<<<NBLK, 512, 0, stream>>>(srcA, dstA, E, N, cnt);
    k_scanrel<<<nb, NBLK, 0, stream>>>(cnt, bucketTotal);
    k_scanbucket<<<1, 512, 0, stream>>>(bucketTotal, nb, bBase, N, offsets);
    k_bin<<<NBLK, 512, 0, stream>>>(srcA, dstA, E, N, cnt, bBase, pair);
    k_csr_local<<<nb, 256, 0, stream>>>(pair, bBase, N, offsets, csr);

    // layer 1
    k_gemm_att<128, 8><<<(N + 63) / 64, 256, 0, stream>>>(x, W1, att_s1, att_d1,
                                                          N, h1bf, as1, ad1);
    k_agg1<<<(N * 64 + 255) / 256, 256, 0, stream>>>(h1bf, as1, ad1, offsets, csr, b1, N, h2in);

    // layer 2
    k_gemm_att<64, 1><<<(N + 63) / 64, 256, 0, stream>>>(h2in, W2, att_s2, att_d2,
                                                         N, h2bf, as2, ad2);
    k_agg2<<<(N * 64 + 255) / 256, 256, 0, stream>>>(h2bf, as2, ad2, offsets, csr, b2, N, (float*)d_out);
}